// Round 2
// baseline (513.345 us; speedup 1.0000x reference)
//
#include <hip/hip_runtime.h>

// ---------------------------------------------------------------------------
// LayerStacks (NNUE-style) on MI355X.
//   h0 = clamp01( x @ (w0[b]+w_fact)^T + b0[b] )   // 1024 -> 32, bf16 MFMA
//   h1 = clamp01( h0 @ w1[b]^T + b1[b] )           // 32 -> 32,  fp32 VALU
//   out = h1 @ w2[b]^T + b2[b]                     // 32 -> 1,   fp32 VALU
// R4: no sort; all 8 buckets computed per row (MFMA nearly free), per-row
// select in epilogue. R5: R4 was latency-bound (occ 20%, all pipes <8%,
// 0.8 TB/s): 70 KB LDS tile -> 2 blocks/CU, and stage->barrier->MFMA->barrier
// serialized ~108k cyc/block. Fix: NO x-staging at all. A-fragments are
// built directly from global (per c, lanes l/l+32 cover one contiguous 64-B
// line per row; c-offsets fold into the 13-bit imm), fp32->bf16 via
// v_cvt_pk_bf16_f32 in-register. LDS drops to ~5 KB; launch_bounds(256,4)
// -> ~16 waves/CU. Weights stay L2-resident bf16 frags from k_prep.
// ---------------------------------------------------------------------------

#define B_ROWS 65536
#define LK     1024       // 2*L1
#define TILE   32
#define NBLK   (B_ROWS / TILE)   // 2048, exact

// ws layout (bytes):
//   [0, 524288) : wB bf16 B-frags of (w0+w_fact): per bucket 4096 uint4;
//                 frag idx c*64+l holds W[bkt*32 + (l&31)][16c + 8*(l>>5) .. +8]

typedef short  short8  __attribute__((ext_vector_type(8)));
typedef float  f32x16  __attribute__((ext_vector_type(16)));

__device__ __forceinline__ unsigned pkbf(float a, float b) {
    // round-to-nearest-even fp32 -> bf16, packed pair (bit-trick, host-free)
    unsigned ua = __float_as_uint(a), ub = __float_as_uint(b);
    ua = (ua + 0x7FFFu + ((ua >> 16) & 1u)) >> 16;
    ub = (ub + 0x7FFFu + ((ub >> 16) & 1u)) >> 16;
    return (ua & 0xFFFFu) | (ub << 16);
}

__device__ __forceinline__ unsigned cvtpk(float a, float b) {
    // RTNE fp32->bf16 packed pair, single instruction on gfx950
    unsigned r;
    asm("v_cvt_pk_bf16_f32 %0, %1, %2" : "=v"(r) : "v"(a), "v"(b));
    return r;
}

// ls_indices may be int32 or int64. If int64, the high words (odd int32
// slots) of the first 64 elements are all zero (values 0..7). Deterministic.
__device__ __forceinline__ bool detect_i64(const int* p) {
    int acc = 0;
#pragma unroll
    for (int i = 0; i < 64; ++i) acc |= p[2 * i + 1];
    return acc == 0;
}

__device__ __forceinline__ int load_bucket(const int* p, int r, bool i64) {
    return (i64 ? p[2 * r] : p[r]) & 7;
}

// --- K1: weight prep only ---------------------------------------------------
// 32 blocks x 1024 thr: build bf16 B-fragments of (w0+w_fact). 1 frag/thread.
__global__ __launch_bounds__(1024) void k_prep(
    const float* __restrict__ w0, const float* __restrict__ wf,
    uint4* __restrict__ wB)
{
    int f = blockIdx.x * 1024 + threadIdx.x;   // 32768 frags
    int b   = f >> 12;
    int i12 = f & 4095;
    int kc  = i12 >> 8;
    int i8  = i12 & 255;
    int n   = i8 & 31;
    int khi = i8 >> 5;
    int k = kc * 64 + khi * 8;                 // == c*16 + 8*(lane>>5)
    const float* p0 = w0 + (size_t)(b * 32 + n) * LK + k;
    const float* pf = wf + (size_t)n * LK + k;
    float v[8];
#pragma unroll
    for (int j = 0; j < 8; ++j) v[j] = p0[j] + pf[j];
    uint4 o;
    o.x = pkbf(v[0], v[1]); o.y = pkbf(v[2], v[3]);
    o.z = pkbf(v[4], v[5]); o.w = pkbf(v[6], v[7]);
    wB[f] = o;
}

// --- K2: main fused kernel ---------------------------------------------------
// Block = 256 thr = 4 waves; tile = 32 consecutive rows. NO LDS x-tile:
// wave wv computes buckets {2wv, 2wv+1} over full K; A-frag for MFMA c is
// read straight from global memory:
//   lane l: x[row0 + (l&31)][c*16 + 8*(l>>5) .. +8]  (2x float4, imm offsets)
// then packed to bf16 via v_cvt_pk. Epilogue selects per-row bucket, then
// layers 1+2 on wave 0 with per-row bucket weights (all L2-resident).
__global__ __launch_bounds__(256, 4) void k_main(
    const float* __restrict__ x, const int* __restrict__ idx,
    const uint4* __restrict__ wB, const float* __restrict__ b0,
    const float* __restrict__ w1, const float* __restrict__ b1,
    const float* __restrict__ w2, const float* __restrict__ b2,
    float* __restrict__ out)
{
    __shared__ float hb[TILE * 36];     // h0, padded rows
    __shared__ int   bkt_s[TILE];

    int row0 = blockIdx.x * TILE;
    int t    = threadIdx.x;
    int lane = t & 63;
    int wv   = t >> 6;

    if (t < TILE) {
        bool i64 = detect_i64(idx);
        bkt_s[t] = load_bucket(idx, row0 + t, i64);
    }
    __syncthreads();   // also aligns the 4 waves entering the loop (L1 lockstep)

    // ---- MFMA: wave wv computes buckets bb0=2wv, bb1=2wv+1 over full K.
    const uint4* wB0 = wB + (size_t)(2 * wv) * 4096;
    const uint4* wB1 = wB0 + 4096;
    const float* Ab  = x + (size_t)(row0 + (lane & 31)) * LK + (lane >> 5) * 8;

    f32x16 acc0, acc1;
#pragma unroll
    for (int i = 0; i < 16; ++i) { acc0[i] = 0.0f; acc1[i] = 0.0f; }

    union UA { uint4 u; short8 s; };
    union UB { uint4 u; short8 s; };
#pragma unroll 4
    for (int c = 0; c < 64; ++c) {
        float4 a0 = *(const float4*)(Ab + c * 16);       // k = 16c + 8*(l>>5) ..
        float4 a1 = *(const float4*)(Ab + c * 16 + 4);   // .. +4..8 (imm offset)
        UB ub0, ub1;
        ub0.u = wB0[c * 64 + lane];                      // L2-resident weights
        ub1.u = wB1[c * 64 + lane];
        UA ua;
        ua.u.x = cvtpk(a0.x, a0.y);
        ua.u.y = cvtpk(a0.z, a0.w);
        ua.u.z = cvtpk(a1.x, a1.y);
        ua.u.w = cvtpk(a1.z, a1.w);
        acc0 = __builtin_amdgcn_mfma_f32_32x32x16_bf16(ua.s, ub0.s, acc0, 0, 0, 0);
        acc1 = __builtin_amdgcn_mfma_f32_32x32x16_bf16(ua.s, ub1.s, acc1, 0, 0, 0);
    }

    // ---- select per-row bucket: C elem (reg i, lane l) is
    //      m = (i&3)+8*(i>>2)+4*(l>>5), n = l&31
    int bb0 = 2 * wv, bb1 = 2 * wv + 1;
#pragma unroll
    for (int i = 0; i < 16; ++i) {
        int m = (i & 3) + 8 * (i >> 2) + 4 * (lane >> 5);
        int n = lane & 31;
        int mb = bkt_s[m];
        if (mb == bb0 || mb == bb1) {
            float s = (mb == bb0) ? acc0[i] : acc1[i];
            float h = s + b0[mb * 32 + n];
            hb[m * 36 + n] = fminf(fmaxf(h, 0.0f), 1.0f);
        }
    }
    __syncthreads();

    // ---- layers 1+2 (fp32), threads 0..63: pair (2r,2r+1) splits 32 outputs
    if (t < 64) {
        int r = t >> 1, half = t & 1;
        int bkt = bkt_s[r];
        const float4* hr = (const float4*)(hb + r * 36);
        float4 ha[8];
#pragma unroll
        for (int q = 0; q < 8; ++q) ha[q] = hr[q];
        const float* w1b = w1 + (size_t)bkt * 1024;
        const float* b1b = b1 + bkt * 32;
        const float* w2b = w2 + bkt * 32;
        float partial = 0.0f;
#pragma unroll
        for (int jj = 0; jj < 16; ++jj) {
            int j2 = half * 16 + jj;
            const float4* wr = (const float4*)&w1b[j2 * 32];
            float s = b1b[j2];
#pragma unroll
            for (int q = 0; q < 8; ++q) {
                float4 w4 = wr[q];
                s += ha[q].x * w4.x + ha[q].y * w4.y + ha[q].z * w4.z + ha[q].w * w4.w;
            }
            s = fminf(fmaxf(s, 0.0f), 1.0f);
            partial += s * w2b[j2];
        }
        partial += __shfl_xor(partial, 1);
        if (half == 0) out[row0 + r] = partial + b2[bkt];
    }
}

// ---------------------------------------------------------------------------
extern "C" void kernel_launch(void* const* d_in, const int* in_sizes, int n_in,
                              void* d_out, int out_size, void* d_ws, size_t ws_size,
                              hipStream_t stream) {
    const float* x   = (const float*)d_in[0];
    const int*   lsi = (const int*)  d_in[1];
    const float* wf  = (const float*)d_in[2];
    const float* w0  = (const float*)d_in[3];
    const float* b0  = (const float*)d_in[4];
    const float* w1  = (const float*)d_in[5];
    const float* b1  = (const float*)d_in[6];
    const float* w2  = (const float*)d_in[7];
    const float* b2  = (const float*)d_in[8];
    float* out = (float*)d_out;

    uint4* wB = (uint4*)d_ws;

    k_prep<<<32, 1024, 0, stream>>>(w0, wf, wB);
    k_main<<<NBLK, 256, 0, stream>>>(x, lsi, wB, b0, w1, b1, w2, b2, out);
}

// Round 3
// 417.321 us; speedup vs baseline: 1.2301x; 1.2301x over previous
//
#include <hip/hip_runtime.h>

// ---------------------------------------------------------------------------
// LayerStacks (NNUE-style) on MI355X.
//   h0 = clamp01( x @ (w0[b]+w_fact)^T + b0[b] )   // 1024 -> 32, bf16 MFMA
//   h1 = clamp01( h0 @ w1[b]^T + b1[b] )           // 32 -> 32,  fp32 VALU
//   out = h1 @ w2[b]^T + b2[b]                     // 32 -> 1,   fp32 VALU
// R4: no sort; all 8 buckets per row (MFMA nearly free), select in epilogue.
// R5 (FAILED, 250us): direct-global A-frags = 32 cache lines per vmem inst,
// TA-serialized. Lesson: A-path must be coalesced-staged through LDS.
// R6: R4's coalesced staging + K-chunked double buffer (4 chunks of 256):
// LDS 2x16.6KB -> 4 blocks/CU (was 2 with 70KB tile), and per-chunk pipeline
// {issue loads chunk+1 -> MFMA chunk -> pack/write chunk+1 -> barrier} hides
// stage latency under MFMA. One barrier per chunk.
// ---------------------------------------------------------------------------

#define B_ROWS 65536
#define LK     1024       // 2*L1
#define TILE   32
#define NBLK   (B_ROWS / TILE)   // 2048, exact
#define KC     256        // K-chunk (bf16 elems)
#define NCH    (LK / KC)  // 4
#define SROW   520        // LDS row stride bytes (512 data + 8 pad): 2-way-free

// ws layout (bytes):
//   [0, 524288) : wB bf16 B-frags of (w0+w_fact): per bucket 4096 uint4;
//                 frag idx c*64+l holds W[bkt*32 + (l&31)][16c + 8*(l>>5) .. +8]

typedef short  short8  __attribute__((ext_vector_type(8)));
typedef float  f32x16  __attribute__((ext_vector_type(16)));

__device__ __forceinline__ unsigned pkbf(float a, float b) {
    // round-to-nearest-even fp32 -> bf16, packed pair (bit-trick)
    unsigned ua = __float_as_uint(a), ub = __float_as_uint(b);
    ua = (ua + 0x7FFFu + ((ua >> 16) & 1u)) >> 16;
    ub = (ub + 0x7FFFu + ((ub >> 16) & 1u)) >> 16;
    return (ua & 0xFFFFu) | (ub << 16);
}

__device__ __forceinline__ unsigned cvtpk(float a, float b) {
    // RTNE fp32->bf16 packed pair, single instruction on gfx950
    unsigned r;
    asm("v_cvt_pk_bf16_f32 %0, %1, %2" : "=v"(r) : "v"(a), "v"(b));
    return r;
}

// ls_indices may be int32 or int64. If int64, the high words (odd int32
// slots) of the first 64 elements are all zero (values 0..7). Deterministic.
__device__ __forceinline__ bool detect_i64(const int* p) {
    int acc = 0;
#pragma unroll
    for (int i = 0; i < 64; ++i) acc |= p[2 * i + 1];
    return acc == 0;
}

__device__ __forceinline__ int load_bucket(const int* p, int r, bool i64) {
    return (i64 ? p[2 * r] : p[r]) & 7;
}

// --- K1: weight prep only ---------------------------------------------------
// 32 blocks x 1024 thr: build bf16 B-fragments of (w0+w_fact). 1 frag/thread.
__global__ __launch_bounds__(1024) void k_prep(
    const float* __restrict__ w0, const float* __restrict__ wf,
    uint4* __restrict__ wB)
{
    int f = blockIdx.x * 1024 + threadIdx.x;   // 32768 frags
    int b   = f >> 12;
    int i12 = f & 4095;
    int kc  = i12 >> 8;
    int i8  = i12 & 255;
    int n   = i8 & 31;
    int khi = i8 >> 5;
    int k = kc * 64 + khi * 8;                 // == c*16 + 8*(lane>>5)
    const float* p0 = w0 + (size_t)(b * 32 + n) * LK + k;
    const float* pf = wf + (size_t)n * LK + k;
    float v[8];
#pragma unroll
    for (int j = 0; j < 8; ++j) v[j] = p0[j] + pf[j];
    uint4 o;
    o.x = pkbf(v[0], v[1]); o.y = pkbf(v[2], v[3]);
    o.z = pkbf(v[4], v[5]); o.w = pkbf(v[6], v[7]);
    wB[f] = o;
}

// --- K2: main fused kernel ---------------------------------------------------
// Block = 256 thr = 4 waves; tile = 32 consecutive rows. K double-buffered in
// chunks of 256: stage chunk (coalesced float4, pack bf16, ds_write_b64),
// wave wv MFMAs buckets {2wv,2wv+1} on the previous chunk. Epilogue selects
// per-row bucket; layers 1+2 fp32 on wave 0 (weights L2-resident).
__global__ __launch_bounds__(256, 4) void k_main(
    const float* __restrict__ x, const int* __restrict__ idx,
    const uint4* __restrict__ wB, const float* __restrict__ b0,
    const float* __restrict__ w1, const float* __restrict__ b1,
    const float* __restrict__ w2, const float* __restrict__ b2,
    float* __restrict__ out)
{
    __shared__ __align__(16) unsigned char a_s[2 * TILE * SROW];  // 33280 B
    __shared__ float hb[TILE * 36];     // h0, padded rows
    __shared__ int   bkt_s[TILE];

    int row0 = blockIdx.x * TILE;
    int t    = threadIdx.x;
    int lane = t & 63;
    int wv   = t >> 6;

    if (t < TILE) {
        bool i64 = detect_i64(idx);
        bkt_s[t] = load_bucket(idx, row0 + t, i64);
    }

    // staging geometry: flat float4 index f = t + 256q -> row = (t>>6)+4q,
    // col4 = t&63. Per wave: 64 consecutive float4 = 1 KB contiguous. q steps
    // 4 rows. Whole chunk = 32 rows x 1 KB, fully coalesced.
    const float4* gsrc = (const float4*)(x + (size_t)(row0 + (t >> 6)) * LK)
                         + (t & 63);
    const int wb_off = (t >> 6) * SROW + (t & 63) * 8;

    // ---- prologue: stage chunk 0 into buf0
    float4 v[8];
#pragma unroll
    for (int q = 0; q < 8; ++q) v[q] = gsrc[q * 1024];
#pragma unroll
    for (int q = 0; q < 8; ++q) {
        uint2 o; o.x = cvtpk(v[q].x, v[q].y); o.y = cvtpk(v[q].z, v[q].w);
        *(uint2*)(a_s + wb_off + q * 4 * SROW) = o;
    }
    __syncthreads();

    const uint4* wB0 = wB + (size_t)(2 * wv) * 4096;
    const uint4* wB1 = wB0 + 4096;

    f32x16 acc0, acc1;
#pragma unroll
    for (int i = 0; i < 16; ++i) { acc0[i] = 0.0f; acc1[i] = 0.0f; }

    union UA { uint2 h[2]; short8 s; };
    union UB { uint4 u;    short8 s; };

    for (int ck = 0; ck < NCH; ++ck) {
        const unsigned char* cur = a_s + (ck & 1) * (TILE * SROW);
        unsigned char* nxt = a_s + ((ck + 1) & 1) * (TILE * SROW);
        bool pf = (ck + 1 < NCH);

        // issue next chunk's global loads early (latency hides under MFMA)
        if (pf) {
#pragma unroll
            for (int q = 0; q < 8; ++q) v[q] = gsrc[(ck + 1) * 64 + q * 1024];
        }

        // MFMA on current chunk: 16 c-steps x 2 buckets
        const unsigned char* Ab = cur + (size_t)(lane & 31) * SROW
                                      + 16 * (lane >> 5);
#pragma unroll
        for (int cc = 0; cc < 16; ++cc) {
            int c = ck * 16 + cc;
            UA ua;
            ua.h[0] = *(const uint2*)(Ab + 32 * cc);      // 2-way alias = free
            ua.h[1] = *(const uint2*)(Ab + 32 * cc + 8);
            UB ub0, ub1;
            ub0.u = wB0[c * 64 + lane];                   // L2-resident
            ub1.u = wB1[c * 64 + lane];
            acc0 = __builtin_amdgcn_mfma_f32_32x32x16_bf16(ua.s, ub0.s, acc0, 0, 0, 0);
            acc1 = __builtin_amdgcn_mfma_f32_32x32x16_bf16(ua.s, ub1.s, acc1, 0, 0, 0);
        }

        // pack + write next chunk into the other buffer
        if (pf) {
#pragma unroll
            for (int q = 0; q < 8; ++q) {
                uint2 o; o.x = cvtpk(v[q].x, v[q].y); o.y = cvtpk(v[q].z, v[q].w);
                *(uint2*)(nxt + wb_off + q * 4 * SROW) = o;
            }
        }
        __syncthreads();
    }

    // ---- select per-row bucket: C elem (reg i, lane l) is
    //      m = (i&3)+8*(i>>2)+4*(l>>5), n = l&31
    int bb0 = 2 * wv, bb1 = 2 * wv + 1;
#pragma unroll
    for (int i = 0; i < 16; ++i) {
        int m = (i & 3) + 8 * (i >> 2) + 4 * (lane >> 5);
        int n = lane & 31;
        int mb = bkt_s[m];
        if (mb == bb0 || mb == bb1) {
            float s = (mb == bb0) ? acc0[i] : acc1[i];
            float h = s + b0[mb * 32 + n];
            hb[m * 36 + n] = fminf(fmaxf(h, 0.0f), 1.0f);
        }
    }
    __syncthreads();

    // ---- layers 1+2 (fp32), threads 0..63: pair (2r,2r+1) splits 32 outputs
    if (t < 64) {
        int r = t >> 1, half = t & 1;
        int bkt = bkt_s[r];
        const float4* hr = (const float4*)(hb + r * 36);
        float4 ha[8];
#pragma unroll
        for (int q = 0; q < 8; ++q) ha[q] = hr[q];
        const float* w1b = w1 + (size_t)bkt * 1024;
        const float* b1b = b1 + bkt * 32;
        const float* w2b = w2 + bkt * 32;
        float partial = 0.0f;
#pragma unroll
        for (int jj = 0; jj < 16; ++jj) {
            int j2 = half * 16 + jj;
            const float4* wr = (const float4*)&w1b[j2 * 32];
            float s = b1b[j2];
#pragma unroll
            for (int q = 0; q < 8; ++q) {
                float4 w4 = wr[q];
                s += ha[q].x * w4.x + ha[q].y * w4.y + ha[q].z * w4.z + ha[q].w * w4.w;
            }
            s = fminf(fmaxf(s, 0.0f), 1.0f);
            partial += s * w2b[j2];
        }
        partial += __shfl_xor(partial, 1);
        if (half == 0) out[row0 + r] = partial + b2[bkt];
    }
}

// ---------------------------------------------------------------------------
extern "C" void kernel_launch(void* const* d_in, const int* in_sizes, int n_in,
                              void* d_out, int out_size, void* d_ws, size_t ws_size,
                              hipStream_t stream) {
    const float* x   = (const float*)d_in[0];
    const int*   lsi = (const int*)  d_in[1];
    const float* wf  = (const float*)d_in[2];
    const float* w0  = (const float*)d_in[3];
    const float* b0  = (const float*)d_in[4];
    const float* w1  = (const float*)d_in[5];
    const float* b1  = (const float*)d_in[6];
    const float* w2  = (const float*)d_in[7];
    const float* b2  = (const float*)d_in[8];
    float* out = (float*)d_out;

    uint4* wB = (uint4*)d_ws;

    k_prep<<<32, 1024, 0, stream>>>(w0, wf, wB);
    k_main<<<NBLK, 256, 0, stream>>>(x, lsi, wB, b0, w1, b1, w2, b2, out);
}